// Round 8
// baseline (290.125 us; speedup 1.0000x reference)
//
#include <hip/hip_runtime.h>

typedef short bf16x8 __attribute__((ext_vector_type(8)));
typedef short bf16x4 __attribute__((ext_vector_type(4)));
typedef short bf16x2 __attribute__((ext_vector_type(2)));
typedef _Float16 f16x8 __attribute__((ext_vector_type(8)));
typedef float f32x4 __attribute__((ext_vector_type(4)));

#define LOG2E 1.4426950408889634f

static __device__ __forceinline__ unsigned short f2bf(float x) {
  unsigned int u = __builtin_bit_cast(unsigned int, x);
  u += 0x7fffu + ((u >> 16) & 1u);
  return (unsigned short)(u >> 16);
}
static __device__ __forceinline__ float bf2f(unsigned short h) {
  unsigned int u = ((unsigned int)h) << 16;
  return __builtin_bit_cast(float, u);
}

static __device__ __forceinline__ void gl_lds16(const void* g, void* l) {
  __builtin_amdgcn_global_load_lds(
      (const __attribute__((address_space(1))) void*)g,
      (__attribute__((address_space(3))) void*)l, 16, 0, 0);
}

// ---------------------------------------------------------------------------
// Prep: K -> fp16 in EXACT MFMA B-fragment order (frag nk = nt*2+ks, lane L,
// j: K[nt*16 + (L&15)][ks*32 + (L>>4)*8 + j]) so the main kernel loads K
// fragments straight from global into registers (no LDS round-trip).
// V -> bf16 transposed, pre-swizzled LDS image (unchanged).
// ws: [Kfrag 8MB][Vt 8MB], tile = (bh*32+kt), each tile 4096 half/short.
// ---------------------------------------------------------------------------
__global__ __launch_bounds__(256)
void prep_kv(const float* __restrict__ K, const float* __restrict__ V,
             short* __restrict__ ws) {
  __shared__ float tmp[64 * 65];
  const int isV = blockIdx.x >> 10;
  const int tile = blockIdx.x & 1023;
  const int bh = tile >> 5, kt = tile & 31;
  const int b = bh >> 4, h = bh & 15;
  const int tid = threadIdx.x;
  if (!isV) {
    const float* Kb = K + ((size_t)b * 2048 + kt * 64) * 1024 + h * 64;
    short* okf = ws + (size_t)tile * 4096;
    for (int i = 0; i < 2; ++i) {
      const int chunk = tid + 256 * i;        // (nk)*64 + L
      const int nk = chunk >> 6, L = chunk & 63;
      const int nt = nk >> 1, ks = nk & 1;
      const int row = nt * 16 + (L & 15);
      const int col = ks * 32 + (L >> 4) * 8;
      const float* src = Kb + (size_t)row * 1024 + col;
      const f32x4 a = *(const f32x4*)src;
      const f32x4 d = *(const f32x4*)(src + 4);
      f16x8 hk;
      for (int j = 0; j < 4; ++j) hk[j] = (_Float16)a[j];
      for (int j = 0; j < 4; ++j) hk[4 + j] = (_Float16)d[j];
      *(f16x8*)(okf + chunk * 8) = hk;
    }
  } else {
    const float* Vb = V + ((size_t)b * 2048 + kt * 64) * 1024 + h * 64;
    short* ovt = ws + 4194304 + (size_t)tile * 4096;
    for (int i = 0; i < 4; ++i) {
      const int idx = tid + 256 * i;
      const int row = idx >> 4, c4 = idx & 15;
      const f32x4 v = *(const f32x4*)(Vb + (size_t)row * 1024 + c4 * 4);
      for (int j = 0; j < 4; ++j) tmp[row * 65 + c4 * 4 + j] = v[j];
    }
    __syncthreads();
    for (int i = 0; i < 2; ++i) {
      const int chunk = tid + 256 * i;        // e*8 + p
      const int e = chunk >> 3, p = chunk & 7;
      const int s0 = (p ^ (e & 7)) * 8;
      bf16x8 o;
      for (int j = 0; j < 8; ++j) o[j] = (short)f2bf(tmp[(s0 + j) * 65 + e]);
      *(bf16x8*)(ovt + chunk * 8) = o;
    }
  }
}

// ---------------------------------------------------------------------------
// Main: one 64-row q-tile per 256-thread block (4 waves x 16 rows), BK=64.
// K fragments register-resident, loaded directly from frag-ordered ws
// (double-buffered in registers, loaded one tile ahead after GEMM1);
// V double-buffered in LDS via global_load_lds DMA; P via LDS (wave-private).
// GEMM1 fp16 (Q hi/lo of LOG2E*q), GEMM2 bf16. Fixed-base softmax (m=0),
// row sums via MFMA-with-ones, truncating f32->bf16 P. Grid 32 x 32, heavy
// qt first. LDS 24KB/block -> residency limited by grid (4/CU), not LDS.
// ---------------------------------------------------------------------------
__global__ __launch_bounds__(256, 4)
void fa_fwd2(const float* __restrict__ Qg, const short* __restrict__ ws,
             float* __restrict__ Og) {
  __shared__ short sVt[2][4096];
  __shared__ short sP[4096];

  const int tid = threadIdx.x;
  const int lane = tid & 63;
  const int wv = tid >> 6;
  const int ml = lane & 15, quad = lane >> 4;
  const int bh = blockIdx.x;
  const int b = bh >> 4, h = bh & 15;
  const float* Qb = Qg + (size_t)b * 2048 * 1024 + h * 64;
  float* Ob = Og + (size_t)b * 2048 * 1024 + h * 64;
  const short* wsKf = ws;
  const short* wsVt = ws + 4194304;
  const int wrow0 = wv * 16;
  const bf16x8 ones = {16256, 16256, 16256, 16256, 16256, 16256, 16256, 16256};
  const f32x4 vzero = {0.f, 0.f, 0.f, 0.f};

  const int qt = 31 - (int)blockIdx.y;   // heavy first
  const int qbase = qt * 64;
  const int nkt = qt + 1;

  // Q fragments (f16 hi/lo of LOG2E*q), registers for the whole tile
  f16x8 qhi[2], qlo[2];
  {
    const float* qr = Qb + (size_t)(qbase + wrow0 + ml) * 1024;
    for (int ks = 0; ks < 2; ++ks) {
      const int e0 = ks * 32 + quad * 8;
      const f32x4 a = *(const f32x4*)(qr + e0);
      const f32x4 c4 = *(const f32x4*)(qr + e0 + 4);
      for (int j = 0; j < 4; ++j) {
        const float x = a[j] * LOG2E;
        const _Float16 hb = (_Float16)x;
        qhi[ks][j] = hb;
        qlo[ks][j] = (_Float16)(x - (float)hb);
      }
      for (int j = 0; j < 4; ++j) {
        const float x = c4[j] * LOG2E;
        const _Float16 hb = (_Float16)x;
        qhi[ks][4 + j] = hb;
        qlo[ks][4 + j] = (_Float16)(x - (float)hb);
      }
    }
  }

  f32x4 acc[4];
  f32x4 accl = vzero;
  for (int et = 0; et < 4; ++et) acc[et] = vzero;

  // K fragments: register double-buffer, loaded straight from global
  f16x8 kfrag[2][8];
  auto loadK = [&](int kt, int bf) {
    const short* g = wsKf + ((size_t)bh * 32 + kt) * 4096;
#pragma unroll
    for (int i = 0; i < 8; ++i)
      kfrag[bf][i] = *(const f16x8*)(g + (i * 64 + lane) * 8);
  };

  // stage V tile kt into LDS buffer bf (2 x 16B DMA per thread)
  auto stageV = [&](int kt, int bf) {
    const short* g2 = wsVt + ((size_t)bh * 32 + kt) * 4096;
    const int o0 = tid * 8, o1 = (tid + 256) * 8;
    gl_lds16(g2 + o0, &sVt[bf][o0]);
    gl_lds16(g2 + o1, &sVt[bf][o1]);
  };

  loadK(0, 0);
  stageV(0, 0);
  __syncthreads();

#pragma unroll 2
  for (int kt = 0; kt < nkt; ++kt) {
    const int buf = kt & 1;
    if (kt + 1 < nkt) stageV(kt + 1, buf ^ 1);  // DMA hidden behind this iter

    // ---- GEMM1 (fp16): S = (log2e Q) K^T, K frags from registers ----
    f32x4 S[4];
    for (int nt = 0; nt < 4; ++nt) S[nt] = vzero;
    for (int ks = 0; ks < 2; ++ks)
      for (int nt = 0; nt < 4; ++nt) {
        const f16x8 kh = kfrag[buf][nt * 2 + ks];
        S[nt] = __builtin_amdgcn_mfma_f32_16x16x32_f16(qhi[ks], kh, S[nt], 0, 0, 0);
        S[nt] = __builtin_amdgcn_mfma_f32_16x16x32_f16(qlo[ks], kh, S[nt], 0, 0, 0);
      }

    // prefetch next K tile into the other register buffer (hidden by exp+GEMM2)
    if (kt + 1 < nkt) loadK(kt + 1, buf ^ 1);

    // ---- p = exp2(S), mask, truncate-to-bf16 -> sP (wave-private rows) ----
    const bool dg = (kt * 64 + 63) > (qbase + wrow0);
    for (int nt = 0; nt < 4; ++nt)
      for (int r = 0; r < 4; ++r) {
        float p = __builtin_amdgcn_exp2f(S[nt][r]);
        if (dg) {
          const int sg = kt * 64 + nt * 16 + ml;
          const int lg = qbase + wrow0 + quad * 4 + r;
          if (sg > lg) p = 0.f;
        }
        const int pr = wrow0 + quad * 4 + r;
        const int s = nt * 16 + ml;
        sP[pr * 64 + (((s >> 3) ^ (pr & 7)) << 3) + (s & 7)] =
            (short)(__builtin_bit_cast(unsigned int, p) >> 16);
      }

    // ---- GEMM2 (bf16): O += P V ; l += P . ones (sP wave-private) ----
    for (int ks = 0; ks < 2; ++ks) {
      const int ch = (ks << 2) + quad;
      const int lrow = wrow0 + ml;
      const bf16x8 pa = *(const bf16x8*)(&sP[lrow * 64 + ((ch ^ (lrow & 7)) << 3)]);
      accl = __builtin_amdgcn_mfma_f32_16x16x32_bf16(pa, ones, accl, 0, 0, 0);
      for (int et = 0; et < 4; ++et) {
        const int e = et * 16 + ml;
        const bf16x8 vb = *(const bf16x8*)(&sVt[buf][e * 64 + ((ch ^ (e & 7)) << 3)]);
        acc[et] = __builtin_amdgcn_mfma_f32_16x16x32_bf16(pa, vb, acc[et], 0, 0, 0);
      }
    }
    __syncthreads();   // drains next-tile V DMA + LDS reuse barrier
  }

  // ---- epilogue: O = acc / l ----
  for (int r = 0; r < 4; ++r) {
    const float inv = 1.0f / accl[r];
    float* orow = Ob + (size_t)(qbase + wrow0 + quad * 4 + r) * 1024;
    for (int et = 0; et < 4; ++et)
      orow[et * 16 + ml] = acc[et][r] * inv;
  }
}

// ---------------------------------------------------------------------------
// Fallback (proven round-2 kernel) for small ws_size.
// ---------------------------------------------------------------------------
__global__ __launch_bounds__(512, 2)
void fa_fwd_fb(const float* __restrict__ Qg, const float* __restrict__ Kg,
               const float* __restrict__ Vg, float* __restrict__ Og) {
  constexpr int HE = 1024, Lr = 2048;
  __shared__ short sKhi[2][64 * 64];
  __shared__ short sKlo[2][64 * 64];
  __shared__ short sVt[2][64 * 64];
  __shared__ short sP[128 * 64];

  const int tid = threadIdx.x;
  const int lane = tid & 63;
  const int wv = tid >> 6;
  const int ml = lane & 15;
  const int quad = lane >> 4;

  const int b = blockIdx.x >> 4, h = blockIdx.x & 15;
  const size_t headoff = (size_t)b * (size_t)Lr * HE + (size_t)h * 64;
  const float* Qb = Qg + headoff;
  const float* Kb = Kg + headoff;
  const float* Vb = Vg + headoff;
  float* Ob = Og + headoff;

  const f32x4 vzero = {0.f, 0.f, 0.f, 0.f};

  for (int half = 0; half < 2; ++half) {
    const int qt = half ? (15 - (int)blockIdx.y) : (int)blockIdx.y;
    const int qbase = qt * 128;
    const int wrow0 = wv * 16;

    bf16x8 qhi[2], qlo[2];
    {
      const float* qr = Qb + (size_t)(qbase + wrow0 + ml) * HE;
      for (int ks = 0; ks < 2; ++ks) {
        const int e0 = ks * 32 + quad * 8;
        const f32x4 a = *(const f32x4*)(qr + e0);
        const f32x4 c4 = *(const f32x4*)(qr + e0 + 4);
        for (int j = 0; j < 4; ++j) {
          const unsigned short hb = f2bf(a[j]);
          qhi[ks][j] = (short)hb;
          qlo[ks][j] = (short)f2bf(a[j] - bf2f(hb));
        }
        for (int j = 0; j < 4; ++j) {
          const unsigned short hb = f2bf(c4[j]);
          qhi[ks][4 + j] = (short)hb;
          qlo[ks][4 + j] = (short)f2bf(c4[j] - bf2f(hb));
        }
      }
    }

    f32x4 acc[4];
    float mrun[4], lrun[4];
    for (int et = 0; et < 4; ++et) acc[et] = vzero;
    for (int r = 0; r < 4; ++r) { mrun[r] = -1e30f; lrun[r] = 0.f; }

    const int nkt = 2 * qt + 2;
    for (int kt = 0; kt < nkt; ++kt) {
      const int buf = kt & 1;
      for (int i = 0; i < 2; ++i) {
        const int idx = tid + 512 * i;
        const int row = idx >> 4, c = idx & 15;
        const f32x4 kv = *(const f32x4*)(Kb + (size_t)(kt * 64 + row) * HE + c * 4);
        bf16x4 hi, lo;
        for (int j = 0; j < 4; ++j) {
          const unsigned short hb = f2bf(kv[j]);
          hi[j] = (short)hb;
          lo[j] = (short)f2bf(kv[j] - bf2f(hb));
        }
        const int off = row * 64 + (((c >> 1) ^ (row & 7)) << 3) + ((c & 1) << 2);
        *(bf16x4*)(&sKhi[buf][off]) = hi;
        *(bf16x4*)(&sKlo[buf][off]) = lo;
      }
      {
        const int c = tid & 15, rb = tid >> 4;
        const int s0 = rb * 2;
        const f32x4 v0 = *(const f32x4*)(Vb + (size_t)(kt * 64 + s0) * HE + c * 4);
        const f32x4 v1 = *(const f32x4*)(Vb + (size_t)(kt * 64 + s0 + 1) * HE + c * 4);
        for (int j = 0; j < 4; ++j) {
          const int e = c * 4 + j;
          bf16x2 p;
          p[0] = (short)f2bf(v0[j]);
          p[1] = (short)f2bf(v1[j]);
          const int off = e * 64 + (((s0 >> 3) ^ (e & 7)) << 3) + (s0 & 7);
          *(bf16x2*)(&sVt[buf][off]) = p;
        }
      }
      __syncthreads();

      f32x4 S[4];
      for (int nt = 0; nt < 4; ++nt) S[nt] = vzero;
      for (int ks = 0; ks < 2; ++ks) {
        const int ch = (ks << 2) + quad;
        for (int nt = 0; nt < 4; ++nt) {
          const int srow = nt * 16 + ml;
          const int off = srow * 64 + ((ch ^ (srow & 7)) << 3);
          const bf16x8 kh = *(const bf16x8*)(&sKhi[buf][off]);
          const bf16x8 kl = *(const bf16x8*)(&sKlo[buf][off]);
          S[nt] = __builtin_amdgcn_mfma_f32_16x16x32_bf16(qhi[ks], kh, S[nt], 0, 0, 0);
          S[nt] = __builtin_amdgcn_mfma_f32_16x16x32_bf16(qlo[ks], kh, S[nt], 0, 0, 0);
          S[nt] = __builtin_amdgcn_mfma_f32_16x16x32_bf16(qhi[ks], kl, S[nt], 0, 0, 0);
        }
      }

      if (kt * 64 + 63 > qbase + wrow0) {
        for (int nt = 0; nt < 4; ++nt)
          for (int r = 0; r < 4; ++r) {
            const int sg = kt * 64 + nt * 16 + ml;
            const int lg = qbase + wrow0 + quad * 4 + r;
            if (sg > lg) S[nt][r] = -1e30f;
          }
      }

      float mnew[4], al[4], rsum[4];
      for (int r = 0; r < 4; ++r) {
        float mx = fmaxf(fmaxf(S[0][r], S[1][r]), fmaxf(S[2][r], S[3][r]));
        mx = fmaxf(mx, __shfl_xor(mx, 1));
        mx = fmaxf(mx, __shfl_xor(mx, 2));
        mx = fmaxf(mx, __shfl_xor(mx, 4));
        mx = fmaxf(mx, __shfl_xor(mx, 8));
        mnew[r] = fmaxf(mrun[r], mx);
        al[r] = __builtin_amdgcn_exp2f((mrun[r] - mnew[r]) * LOG2E);
        mrun[r] = mnew[r];
        rsum[r] = 0.f;
      }
      for (int nt = 0; nt < 4; ++nt)
        for (int r = 0; r < 4; ++r) {
          const float p = __builtin_amdgcn_exp2f((S[nt][r] - mnew[r]) * LOG2E);
          S[nt][r] = p;
          rsum[r] += p;
        }
      for (int r = 0; r < 4; ++r) {
        rsum[r] += __shfl_xor(rsum[r], 1);
        rsum[r] += __shfl_xor(rsum[r], 2);
        rsum[r] += __shfl_xor(rsum[r], 4);
        rsum[r] += __shfl_xor(rsum[r], 8);
        lrun[r] = lrun[r] * al[r] + rsum[r];
      }
      for (int et = 0; et < 4; ++et)
        for (int r = 0; r < 4; ++r) acc[et][r] *= al[r];

      for (int nt = 0; nt < 4; ++nt)
        for (int r = 0; r < 4; ++r) {
          const int pr = wrow0 + quad * 4 + r;
          const int s = nt * 16 + ml;
          sP[pr * 64 + (((s >> 3) ^ (pr & 7)) << 3) + (s & 7)] = (short)f2bf(S[nt][r]);
        }

      for (int ks = 0; ks < 2; ++ks) {
        const int ch = (ks << 2) + quad;
        const int lrow = wrow0 + ml;
        const bf16x8 pa = *(const bf16x8*)(&sP[lrow * 64 + ((ch ^ (lrow & 7)) << 3)]);
        for (int et = 0; et < 4; ++et) {
          const int e = et * 16 + ml;
          const bf16x8 vb = *(const bf16x8*)(&sVt[buf][e * 64 + ((ch ^ (e & 7)) << 3)]);
          acc[et] = __builtin_amdgcn_mfma_f32_16x16x32_bf16(pa, vb, acc[et], 0, 0, 0);
        }
      }
    }

    for (int r = 0; r < 4; ++r) {
      const float inv = 1.0f / lrun[r];
      float* orow = Ob + (size_t)(qbase + wrow0 + quad * 4 + r) * HE;
      for (int et = 0; et < 4; ++et)
        orow[et * 16 + ml] = acc[et][r] * inv;
    }
  }
}

extern "C" void kernel_launch(void* const* d_in, const int* in_sizes, int n_in,
                              void* d_out, int out_size, void* d_ws, size_t ws_size,
                              hipStream_t stream) {
  const float* Q = (const float*)d_in[0];
  const float* K = (const float*)d_in[1];
  const float* V = (const float*)d_in[2];
  float* O = (float*)d_out;
  if (ws_size >= 16777216u) {
    short* ws = (short*)d_ws;
    hipLaunchKernelGGL(prep_kv, dim3(2048, 1, 1), dim3(256, 1, 1), 0, stream, K, V, ws);
    hipLaunchKernelGGL(fa_fwd2, dim3(32, 32, 1), dim3(256, 1, 1), 0, stream, Q, ws, O);
  } else {
    hipLaunchKernelGGL(fa_fwd_fb, dim3(32, 8, 1), dim3(512, 1, 1), 0, stream, Q, K, V, O);
  }
}

// Round 9
// 132.044 us; speedup vs baseline: 2.1972x; 2.1972x over previous
//
#include <hip/hip_runtime.h>

typedef short bf16x8 __attribute__((ext_vector_type(8)));
typedef short bf16x4 __attribute__((ext_vector_type(4)));
typedef short bf16x2 __attribute__((ext_vector_type(2)));
typedef _Float16 f16x8 __attribute__((ext_vector_type(8)));
typedef float f32x4 __attribute__((ext_vector_type(4)));

#define LOG2E 1.4426950408889634f

static __device__ __forceinline__ unsigned short f2bf(float x) {
  unsigned int u = __builtin_bit_cast(unsigned int, x);
  u += 0x7fffu + ((u >> 16) & 1u);
  return (unsigned short)(u >> 16);
}
static __device__ __forceinline__ float bf2f(unsigned short h) {
  unsigned int u = ((unsigned int)h) << 16;
  return __builtin_bit_cast(float, u);
}

static __device__ __forceinline__ void gl_lds16(const void* g, void* l) {
  __builtin_amdgcn_global_load_lds(
      (const __attribute__((address_space(1))) void*)g,
      (__attribute__((address_space(3))) void*)l, 16, 0, 0);
}

// ---------------------------------------------------------------------------
// Prep (round-7 proven): K -> fp16 (RNE), V -> bf16 transposed, both
// pre-swizzled into the exact LDS image order. ws: [Kf16 8MB][Vt 8MB],
// tile = (bh*32+kt), each tile 4096 half/short.
// ---------------------------------------------------------------------------
__global__ __launch_bounds__(256)
void prep_kv(const float* __restrict__ K, const float* __restrict__ V,
             short* __restrict__ ws) {
  __shared__ float tmp[64 * 65];
  const int isV = blockIdx.x >> 10;
  const int tile = blockIdx.x & 1023;
  const int bh = tile >> 5, kt = tile & 31;
  const int b = bh >> 4, h = bh & 15;
  const int tid = threadIdx.x;
  if (!isV) {
    const float* Kb = K + ((size_t)b * 2048 + kt * 64) * 1024 + h * 64;
    short* okf = ws + (size_t)tile * 4096;
    for (int i = 0; i < 2; ++i) {
      const int chunk = tid + 256 * i;        // row*8 + p
      const int row = chunk >> 3, p = chunk & 7;
      const int c = p ^ (row & 7);
      const float* src = Kb + (size_t)row * 1024 + c * 8;
      const f32x4 a = *(const f32x4*)src;
      const f32x4 d = *(const f32x4*)(src + 4);
      f16x8 hk;
      for (int j = 0; j < 4; ++j) hk[j] = (_Float16)a[j];
      for (int j = 0; j < 4; ++j) hk[4 + j] = (_Float16)d[j];
      *(f16x8*)(okf + chunk * 8) = hk;
    }
  } else {
    const float* Vb = V + ((size_t)b * 2048 + kt * 64) * 1024 + h * 64;
    short* ovt = ws + 4194304 + (size_t)tile * 4096;
    for (int i = 0; i < 4; ++i) {
      const int idx = tid + 256 * i;
      const int row = idx >> 4, c4 = idx & 15;
      const f32x4 v = *(const f32x4*)(Vb + (size_t)row * 1024 + c4 * 4);
      for (int j = 0; j < 4; ++j) tmp[row * 65 + c4 * 4 + j] = v[j];
    }
    __syncthreads();
    for (int i = 0; i < 2; ++i) {
      const int chunk = tid + 256 * i;        // e*8 + p
      const int e = chunk >> 3, p = chunk & 7;
      const int s0 = (p ^ (e & 7)) * 8;
      bf16x8 o;
      for (int j = 0; j < 8; ++j) o[j] = (short)f2bf(tmp[(s0 + j) * 65 + e]);
      *(bf16x8*)(ovt + chunk * 8) = o;
    }
  }
}

// ---------------------------------------------------------------------------
// Main (round-7 body, CU-balanced qt map): one 64-row q-tile per 256-thread
// block (4 waves x 16 rows), BK=64. K/V double-buffered in LDS via
// global_load_lds DMA pipelined one tile ahead. GEMM1 fp16 (Q hi/lo of
// LOG2E*q), GEMM2 bf16. Fixed-base softmax (m=0), MFMA-ones row sums,
// truncating f32->bf16 P. Grid 32 x 32 = 1024 blocks = 4/CU (LDS 40KB).
// qt map: with round-robin dispatch, CU c hosts y in {a,a+8,a+16,a+24}
// (a=c>>5); qt = {31-a, a, 23-a, 8+a} makes every CU's k-iter sum exactly
// 66 (was 48..80 with qt=31-y -> heavy-CU tail ran at 1 wave/SIMD).
// ---------------------------------------------------------------------------
__global__ __launch_bounds__(256, 4)
void fa_fwd2(const float* __restrict__ Qg, const short* __restrict__ ws,
             float* __restrict__ Og) {
  __shared__ short sKf[2][4096];
  __shared__ short sVt[2][4096];
  __shared__ short sP[4096];

  const int tid = threadIdx.x;
  const int lane = tid & 63;
  const int wv = tid >> 6;
  const int ml = lane & 15, quad = lane >> 4;
  const int bh = blockIdx.x;
  const int b = bh >> 4, h = bh & 15;
  const float* Qb = Qg + (size_t)b * 2048 * 1024 + h * 64;
  float* Ob = Og + (size_t)b * 2048 * 1024 + h * 64;
  const short* wsKf = ws;
  const short* wsVt = ws + 4194304;
  const int wrow0 = wv * 16;
  const bf16x8 ones = {16256, 16256, 16256, 16256, 16256, 16256, 16256, 16256};
  const f32x4 vzero = {0.f, 0.f, 0.f, 0.f};

  // CU-balanced qt permutation (uniform 66 iters per CU; heavy group first)
  const int ya = (int)blockIdx.y & 7, yg = (int)blockIdx.y >> 3;
  const int qt = (yg == 0) ? (31 - ya) : (yg == 1) ? ya : (yg == 2) ? (23 - ya) : (8 + ya);
  const int qbase = qt * 64;
  const int nkt = qt + 1;

  // Q fragments (f16 hi/lo of LOG2E*q), registers for the whole tile
  f16x8 qhi[2], qlo[2];
  {
    const float* qr = Qb + (size_t)(qbase + wrow0 + ml) * 1024;
    for (int ks = 0; ks < 2; ++ks) {
      const int e0 = ks * 32 + quad * 8;
      const f32x4 a = *(const f32x4*)(qr + e0);
      const f32x4 c4 = *(const f32x4*)(qr + e0 + 4);
      for (int j = 0; j < 4; ++j) {
        const float x = a[j] * LOG2E;
        const _Float16 hb = (_Float16)x;
        qhi[ks][j] = hb;
        qlo[ks][j] = (_Float16)(x - (float)hb);
      }
      for (int j = 0; j < 4; ++j) {
        const float x = c4[j] * LOG2E;
        const _Float16 hb = (_Float16)x;
        qhi[ks][4 + j] = hb;
        qlo[ks][4 + j] = (_Float16)(x - (float)hb);
      }
    }
  }

  f32x4 acc[4];
  f32x4 accl = vzero;
  for (int et = 0; et < 4; ++et) acc[et] = vzero;

  // stage tile kt into buffer bf (4 x 16B DMA per thread)
  auto stage = [&](int kt, int bf) {
    const size_t ktile = ((size_t)bh * 32 + kt) * 4096;
    const short* g0 = wsKf + ktile;
    const short* g2 = wsVt + ktile;
    const int o0 = tid * 8, o1 = (tid + 256) * 8;
    gl_lds16(g0 + o0, &sKf[bf][o0]);
    gl_lds16(g0 + o1, &sKf[bf][o1]);
    gl_lds16(g2 + o0, &sVt[bf][o0]);
    gl_lds16(g2 + o1, &sVt[bf][o1]);
  };

  stage(0, 0);
  __syncthreads();

#pragma unroll 2
  for (int kt = 0; kt < nkt; ++kt) {
    const int buf = kt & 1;
    if (kt + 1 < nkt) stage(kt + 1, buf ^ 1);  // hidden behind this iter

    // ---- GEMM1 (fp16): S = (log2e Q) K^T  (qhi + qlo vs f16 K) ----
    f32x4 S[4];
    for (int nt = 0; nt < 4; ++nt) S[nt] = vzero;
    for (int ks = 0; ks < 2; ++ks) {
      const int ch = (ks << 2) + quad;
      for (int nt = 0; nt < 4; ++nt) {
        const int srow = nt * 16 + ml;
        const int off = srow * 64 + ((ch ^ (srow & 7)) << 3);
        const f16x8 kh = *(const f16x8*)(&sKf[buf][off]);
        S[nt] = __builtin_amdgcn_mfma_f32_16x16x32_f16(qhi[ks], kh, S[nt], 0, 0, 0);
        S[nt] = __builtin_amdgcn_mfma_f32_16x16x32_f16(qlo[ks], kh, S[nt], 0, 0, 0);
      }
    }

    // ---- p = exp2(S), mask, truncate-to-bf16 -> sP (wave-private rows) ----
    const bool dg = (kt * 64 + 63) > (qbase + wrow0);
    for (int nt = 0; nt < 4; ++nt)
      for (int r = 0; r < 4; ++r) {
        float p = __builtin_amdgcn_exp2f(S[nt][r]);
        if (dg) {
          const int sg = kt * 64 + nt * 16 + ml;
          const int lg = qbase + wrow0 + quad * 4 + r;
          if (sg > lg) p = 0.f;
        }
        const int pr = wrow0 + quad * 4 + r;
        const int s = nt * 16 + ml;
        sP[pr * 64 + (((s >> 3) ^ (pr & 7)) << 3) + (s & 7)] =
            (short)(__builtin_bit_cast(unsigned int, p) >> 16);
      }

    // ---- GEMM2 (bf16): O += P V ; l += P . ones (sP wave-private) ----
    for (int ks = 0; ks < 2; ++ks) {
      const int ch = (ks << 2) + quad;
      const int lrow = wrow0 + ml;
      const bf16x8 pa = *(const bf16x8*)(&sP[lrow * 64 + ((ch ^ (lrow & 7)) << 3)]);
      accl = __builtin_amdgcn_mfma_f32_16x16x32_bf16(pa, ones, accl, 0, 0, 0);
      for (int et = 0; et < 4; ++et) {
        const int e = et * 16 + ml;
        const bf16x8 vb = *(const bf16x8*)(&sVt[buf][e * 64 + ((ch ^ (e & 7)) << 3)]);
        acc[et] = __builtin_amdgcn_mfma_f32_16x16x32_bf16(pa, vb, acc[et], 0, 0, 0);
      }
    }
    __syncthreads();   // drains next-tile DMA + LDS reuse barrier
  }

  // ---- epilogue: O = acc / l ----
  for (int r = 0; r < 4; ++r) {
    const float inv = 1.0f / accl[r];
    float* orow = Ob + (size_t)(qbase + wrow0 + quad * 4 + r) * 1024;
    for (int et = 0; et < 4; ++et)
      orow[et * 16 + ml] = acc[et][r] * inv;
  }
}

// ---------------------------------------------------------------------------
// Fallback (proven round-2 kernel) for small ws_size.
// ---------------------------------------------------------------------------
__global__ __launch_bounds__(512, 2)
void fa_fwd_fb(const float* __restrict__ Qg, const float* __restrict__ Kg,
               const float* __restrict__ Vg, float* __restrict__ Og) {
  constexpr int HE = 1024, Lr = 2048;
  __shared__ short sKhi[2][64 * 64];
  __shared__ short sKlo[2][64 * 64];
  __shared__ short sVt[2][64 * 64];
  __shared__ short sP[128 * 64];

  const int tid = threadIdx.x;
  const int lane = tid & 63;
  const int wv = tid >> 6;
  const int ml = lane & 15;
  const int quad = lane >> 4;

  const int b = blockIdx.x >> 4, h = blockIdx.x & 15;
  const size_t headoff = (size_t)b * (size_t)Lr * HE + (size_t)h * 64;
  const float* Qb = Qg + headoff;
  const float* Kb = Kg + headoff;
  const float* Vb = Vg + headoff;
  float* Ob = Og + headoff;

  const f32x4 vzero = {0.f, 0.f, 0.f, 0.f};

  for (int half = 0; half < 2; ++half) {
    const int qt = half ? (15 - (int)blockIdx.y) : (int)blockIdx.y;
    const int qbase = qt * 128;
    const int wrow0 = wv * 16;

    bf16x8 qhi[2], qlo[2];
    {
      const float* qr = Qb + (size_t)(qbase + wrow0 + ml) * HE;
      for (int ks = 0; ks < 2; ++ks) {
        const int e0 = ks * 32 + quad * 8;
        const f32x4 a = *(const f32x4*)(qr + e0);
        const f32x4 c4 = *(const f32x4*)(qr + e0 + 4);
        for (int j = 0; j < 4; ++j) {
          const unsigned short hb = f2bf(a[j]);
          qhi[ks][j] = (short)hb;
          qlo[ks][j] = (short)f2bf(a[j] - bf2f(hb));
        }
        for (int j = 0; j < 4; ++j) {
          const unsigned short hb = f2bf(c4[j]);
          qhi[ks][4 + j] = (short)hb;
          qlo[ks][4 + j] = (short)f2bf(c4[j] - bf2f(hb));
        }
      }
    }

    f32x4 acc[4];
    float mrun[4], lrun[4];
    for (int et = 0; et < 4; ++et) acc[et] = vzero;
    for (int r = 0; r < 4; ++r) { mrun[r] = -1e30f; lrun[r] = 0.f; }

    const int nkt = 2 * qt + 2;
    for (int kt = 0; kt < nkt; ++kt) {
      const int buf = kt & 1;
      for (int i = 0; i < 2; ++i) {
        const int idx = tid + 512 * i;
        const int row = idx >> 4, c = idx & 15;
        const f32x4 kv = *(const f32x4*)(Kb + (size_t)(kt * 64 + row) * HE + c * 4);
        bf16x4 hi, lo;
        for (int j = 0; j < 4; ++j) {
          const unsigned short hb = f2bf(kv[j]);
          hi[j] = (short)hb;
          lo[j] = (short)f2bf(kv[j] - bf2f(hb));
        }
        const int off = row * 64 + (((c >> 1) ^ (row & 7)) << 3) + ((c & 1) << 2);
        *(bf16x4*)(&sKhi[buf][off]) = hi;
        *(bf16x4*)(&sKlo[buf][off]) = lo;
      }
      {
        const int c = tid & 15, rb = tid >> 4;
        const int s0 = rb * 2;
        const f32x4 v0 = *(const f32x4*)(Vb + (size_t)(kt * 64 + s0) * HE + c * 4);
        const f32x4 v1 = *(const f32x4*)(Vb + (size_t)(kt * 64 + s0 + 1) * HE + c * 4);
        for (int j = 0; j < 4; ++j) {
          const int e = c * 4 + j;
          bf16x2 p;
          p[0] = (short)f2bf(v0[j]);
          p[1] = (short)f2bf(v1[j]);
          const int off = e * 64 + (((s0 >> 3) ^ (e & 7)) << 3) + (s0 & 7);
          *(bf16x2*)(&sVt[buf][off]) = p;
        }
      }
      __syncthreads();

      f32x4 S[4];
      for (int nt = 0; nt < 4; ++nt) S[nt] = vzero;
      for (int ks = 0; ks < 2; ++ks) {
        const int ch = (ks << 2) + quad;
        for (int nt = 0; nt < 4; ++nt) {
          const int srow = nt * 16 + ml;
          const int off = srow * 64 + ((ch ^ (srow & 7)) << 3);
          const bf16x8 kh = *(const bf16x8*)(&sKhi[buf][off]);
          const bf16x8 kl = *(const bf16x8*)(&sKlo[buf][off]);
          S[nt] = __builtin_amdgcn_mfma_f32_16x16x32_bf16(qhi[ks], kh, S[nt], 0, 0, 0);
          S[nt] = __builtin_amdgcn_mfma_f32_16x16x32_bf16(qlo[ks], kh, S[nt], 0, 0, 0);
          S[nt] = __builtin_amdgcn_mfma_f32_16x16x32_bf16(qhi[ks], kl, S[nt], 0, 0, 0);
        }
      }

      if (kt * 64 + 63 > qbase + wrow0) {
        for (int nt = 0; nt < 4; ++nt)
          for (int r = 0; r < 4; ++r) {
            const int sg = kt * 64 + nt * 16 + ml;
            const int lg = qbase + wrow0 + quad * 4 + r;
            if (sg > lg) S[nt][r] = -1e30f;
          }
      }

      float mnew[4], al[4], rsum[4];
      for (int r = 0; r < 4; ++r) {
        float mx = fmaxf(fmaxf(S[0][r], S[1][r]), fmaxf(S[2][r], S[3][r]));
        mx = fmaxf(mx, __shfl_xor(mx, 1));
        mx = fmaxf(mx, __shfl_xor(mx, 2));
        mx = fmaxf(mx, __shfl_xor(mx, 4));
        mx = fmaxf(mx, __shfl_xor(mx, 8));
        mnew[r] = fmaxf(mrun[r], mx);
        al[r] = __builtin_amdgcn_exp2f((mrun[r] - mnew[r]) * LOG2E);
        mrun[r] = mnew[r];
        rsum[r] = 0.f;
      }
      for (int nt = 0; nt < 4; ++nt)
        for (int r = 0; r < 4; ++r) {
          const float p = __builtin_amdgcn_exp2f((S[nt][r] - mnew[r]) * LOG2E);
          S[nt][r] = p;
          rsum[r] += p;
        }
      for (int r = 0; r < 4; ++r) {
        rsum[r] += __shfl_xor(rsum[r], 1);
        rsum[r] += __shfl_xor(rsum[r], 2);
        rsum[r] += __shfl_xor(rsum[r], 4);
        rsum[r] += __shfl_xor(rsum[r], 8);
        lrun[r] = lrun[r] * al[r] + rsum[r];
      }
      for (int et = 0; et < 4; ++et)
        for (int r = 0; r < 4; ++r) acc[et][r] *= al[r];

      for (int nt = 0; nt < 4; ++nt)
        for (int r = 0; r < 4; ++r) {
          const int pr = wrow0 + quad * 4 + r;
          const int s = nt * 16 + ml;
          sP[pr * 64 + (((s >> 3) ^ (pr & 7)) << 3) + (s & 7)] = (short)f2bf(S[nt][r]);
        }

      for (int ks = 0; ks < 2; ++ks) {
        const int ch = (ks << 2) + quad;
        const int lrow = wrow0 + ml;
        const bf16x8 pa = *(const bf16x8*)(&sP[lrow * 64 + ((ch ^ (lrow & 7)) << 3)]);
        for (int et = 0; et < 4; ++et) {
          const int e = et * 16 + ml;
          const bf16x8 vb = *(const bf16x8*)(&sVt[buf][e * 64 + ((ch ^ (e & 7)) << 3)]);
          acc[et] = __builtin_amdgcn_mfma_f32_16x16x32_bf16(pa, vb, acc[et], 0, 0, 0);
        }
      }
    }

    for (int r = 0; r < 4; ++r) {
      const float inv = 1.0f / lrun[r];
      float* orow = Ob + (size_t)(qbase + wrow0 + quad * 4 + r) * HE;
      for (int et = 0; et < 4; ++et)
        orow[et * 16 + ml] = acc[et][r] * inv;
    }
  }
}

extern "C" void kernel_launch(void* const* d_in, const int* in_sizes, int n_in,
                              void* d_out, int out_size, void* d_ws, size_t ws_size,
                              hipStream_t stream) {
  const float* Q = (const float*)d_in[0];
  const float* K = (const float*)d_in[1];
  const float* V = (const float*)d_in[2];
  float* O = (float*)d_out;
  if (ws_size >= 16777216u) {
    short* ws = (short*)d_ws;
    hipLaunchKernelGGL(prep_kv, dim3(2048, 1, 1), dim3(256, 1, 1), 0, stream, K, V, ws);
    hipLaunchKernelGGL(fa_fwd2, dim3(32, 32, 1), dim3(256, 1, 1), 0, stream, Q, ws, O);
  } else {
    hipLaunchKernelGGL(fa_fwd_fb, dim3(32, 8, 1), dim3(512, 1, 1), 0, stream, Q, K, V, O);
  }
}